// Round 3
// baseline (1296.224 us; speedup 1.0000x reference)
//
#include <hip/hip_runtime.h>

typedef unsigned int uint;
typedef unsigned short ushort;

typedef short bfrag __attribute__((ext_vector_type(8)));   // 8 x bf16 (4 VGPRs)
typedef float f32x4 __attribute__((ext_vector_type(4)));

__device__ __forceinline__ ushort f2bf(float f) {
  uint u = __float_as_uint(f);
  u = (u + 0x7FFFu + ((u >> 16) & 1u)) >> 16;   // RNE
  return (ushort)u;
}
__device__ __forceinline__ float bf2f(ushort h) {
  return __uint_as_float(((uint)h) << 16);
}
// packed fp32x2 -> bf16x2, RNE (bit-identical to f2bf pairs), 1 instruction
__device__ __forceinline__ uint cvt_pk_bf16(float lo, float hi) {
  uint r;
  asm("v_cvt_pk_bf16_f32 %0, %1, %2" : "=v"(r) : "v"(lo), "v"(hi));
  return r;
}
__device__ __forceinline__ float sigmoidf(float t) {
  return __builtin_amdgcn_rcpf(1.0f + __expf(-t));
}
// v + (v from quad_perm partner) via DPP (VALU-latency, not LDS); ctrl must
// be a compile-time constant -> template parameter.
template <int CTRL>
__device__ __forceinline__ float dppadd(float v) {
  int r = __builtin_amdgcn_update_dpp(0, __float_as_int(v), CTRL, 0xf, 0xf, true);
  return v + __int_as_float(r);
}

// ---------------------------------------------------------------------------
// Prep: pack Wq|Wk|Wv (fp32 [H][256][64]) into bf16 MFMA fragment order:
//   wb[gnt][kk][lane][j] = W[k = kk*32 + (lane>>4)*8 + j][n = gnt*16 + (lane&15)]
// (used as the A operand of mfma(W, x): lane&15 = n becomes the output ROW.)
// Also SE weights as A-frags with hi/lo bf16 split (hi+lo ~ fp32 precision):
//   w1b[2][8][64][8]:  A[row=j=l&15][k=c]  = W1[c][j],  c = kk*32+(l>>4)*8+jj
//   w2b[2][16][64][8]: A[row=c][k=j<16]    = W2[j][c],  c = nt*16+(l&15),
//                      j = (l>>4)*8+jj, quads 2,3 = zero (K=32 zero-padded)
// ---------------------------------------------------------------------------
__global__ void prep_kernel(const float* __restrict__ Wq, const float* __restrict__ Wk,
                            const float* __restrict__ Wv, const float* __restrict__ W1,
                            const float* __restrict__ W2,
                            ushort* __restrict__ wb, ushort* __restrict__ w1b,
                            ushort* __restrict__ w2b) {
  int idx = blockIdx.x * 256 + threadIdx.x;
  if (idx < 196608) {
    int j    = idx & 7;
    int lane = (idx >> 3) & 63;
    int kk   = (idx >> 9) & 7;
    int gnt  = idx >> 12;                 // 0..47
    int head = gnt / 12;
    int nh   = (gnt % 12) * 16 + (lane & 15);   // 0..191 within head
    int k    = kk * 32 + (lane >> 4) * 8 + j;   // 0..255
    int sel  = nh >> 6, d = nh & 63;
    const float* W = (sel == 0) ? Wq : ((sel == 1) ? Wk : Wv);
    wb[idx] = f2bf(W[(head * 256 + k) * 64 + d]);
  }
  if (idx < 4096) {
    int jj   = idx & 7;
    int lane = (idx >> 3) & 63;
    int kk   = idx >> 9;
    int c    = kk * 32 + (lane >> 4) * 8 + jj;
    float v  = W1[c * 16 + (lane & 15)];
    ushort h = f2bf(v);
    w1b[idx] = h;
    w1b[4096 + idx] = f2bf(v - bf2f(h));
  }
  if (idx < 8192) {
    int jj   = idx & 7;
    int lane = (idx >> 3) & 63;
    int nt   = idx >> 9;
    int quad = lane >> 4;
    int k    = (quad & 1) * 8 + jj;
    float v  = (quad < 2) ? W2[k * 256 + nt * 16 + (lane & 15)] : 0.f;
    ushort h = f2bf(v);
    w2b[idx] = h;
    w2b[8192 + idx] = f2bf(v - bf2f(h));
  }
}

// ---------------------------------------------------------------------------
// Fused: per block 16 samples (80 x-rows).
//  - stage x fp32->bf16 into swizzled LDS; head0 W-frags prefetched under it
//  - per head: mfma(W,x) K-loop (W from registers, x from LDS), packed qkv
//    writeback; NEXT head's 24 W-frags issued right after the K-loop so they
//    fly across the barrier + attention latency chain (counted-prefetch).
//  - attention via MFMA (as R1) with DPP quad_perm for xor1/xor2 reduce.
//  - SE gate via MFMA: rT = relu(b1 + mfma(W1T,s)) (hi/lo split), r roundtrip
//    through rbuf ALIASED into dead qkv, g = sigmoid(mfma(W2T,r) + b2),
//    direct packed float4 stores. Replaces ~940 VALU/thread tail.
// LDS: x 40960 + qkv 32000 + sbuf 8192 + wgt 512 = 81664 B -> 2 blocks/CU.
// ---------------------------------------------------------------------------
__global__ __launch_bounds__(256, 2)
void fused_kernel(const float* __restrict__ x,
                  const float* __restrict__ bq, const float* __restrict__ bk,
                  const float* __restrict__ bv,
                  const ushort* __restrict__ wb, const ushort* __restrict__ w1b,
                  const ushort* __restrict__ w2b,
                  const float* __restrict__ b1, const float* __restrict__ b2,
                  float* __restrict__ out) {
  __shared__ ushort xlds[20480];   // 80 rows x 256 bf16, 16B-chunk XOR swizzle
  __shared__ ushort qkv[16000];    // 80 rows x 200 bf16 (192 used), 400B row
  __shared__ ushort sbuf[4096];    // s: 16 samples x 256 bf16
  __shared__ float  wgt[128];      // [16][8]: w[sample][m], m=0..4

  const int tid  = threadIdx.x;
  const int lane = tid & 63;
  const int wave = tid >> 6;
  const int ln   = lane & 15;
  const int quad = lane >> 4;
  const int blk  = blockIdx.x;

  // ---- stage x tile: 20480 floats, fully coalesced float4, cvt to bf16
  {
    const float* xb = x + (size_t)blk * 20480;
#pragma unroll
    for (int it = 0; it < 20; ++it) {
      int f = it * 1024 + tid * 4;
      float4 v = *(const float4*)(xb + f);
      int row = f >> 8;
      int col = f & 255;
      int ch = col >> 3;
      int half = (col >> 2) & 1;
      int phys = ch ^ (row & 7);
      uint2 p;
      p.x = cvt_pk_bf16(v.x, v.y);
      p.y = cvt_pk_bf16(v.z, v.w);
      *(uint2*)(&xlds[row * 256 + phys * 8 + half * 4]) = p;
    }
  }

  // ---- head0 W-fragment prefetch (in flight during staging barrier)
  const bfrag* wfr = (const bfrag*)wb;
  bfrag Wc[24];   // [kk][nt]
#pragma unroll
  for (int kk = 0; kk < 8; ++kk)
#pragma unroll
    for (int nt = 0; nt < 3; ++nt)
      Wc[kk * 3 + nt] = wfr[((wave * 3 + nt) * 8 + kk) * 64 + lane];

  __syncthreads();

  const int sample = tid >> 4;   // 0..15
  const int u      = tid & 15;   // 0..15

  // ---- attention lane mapping (head-independent, hoisted)
  const int sl   = ln >> 3;            // which sample within tile (0/1)
  const int mm   = ln & 7;             // m index, pad >=5
  const int qsel = quad - (sl << 1);   // 0: acc rows m=0..3; 1: row m=4
  const bool lo  = (qsel == 0), hi = (qsel == 1);
  const bool lv  = (mm < 5);
  int r0 = (wave * 4 + sl) * 5 + mm;      if (r0 > 79) r0 = 79;  // tile0 rows
  int r1 = (wave * 4 + 2 + sl) * 5 + mm;  if (r1 > 79) r1 = 79;  // tile1 rows
  const int bQ0 = r0 * 400 + quad * 16;   // byte base, Q cols
  const int bQ1 = r1 * 400 + quad * 16;

#pragma unroll 1
  for (int head = 0; head < 4; ++head) {
    f32x4 acc[5][3];   // [mt = xrow tile][nt = n tile]
#pragma unroll
    for (int mt = 0; mt < 5; ++mt)
#pragma unroll
      for (int nt = 0; nt < 3; ++nt)
        acc[mt][nt] = (f32x4){0.f, 0.f, 0.f, 0.f};

    // ---- K-loop: 8 steps of 32. x: ds_read_b128; W: registers
#pragma unroll
    for (int kk = 0; kk < 8; ++kk) {
      bfrag a[5];
      int cb = kk * 4 + quad;
#pragma unroll
      for (int mt = 0; mt < 5; ++mt) {
        int row = mt * 16 + ln;
        int off = row * 256 + ((cb ^ (row & 7)) << 3);
        a[mt] = *(const bfrag*)(&xlds[off]);
      }
#pragma unroll
      for (int nt = 0; nt < 3; ++nt)
#pragma unroll
        for (int mt = 0; mt < 5; ++mt)
          acc[mt][nt] = __builtin_amdgcn_mfma_f32_16x16x32_bf16(Wc[kk * 3 + nt], a[mt], acc[mt][nt], 0, 0, 0);
    }

    // ---- prefetch next head's W-frags (fly across barrier + attention)
    bfrag Wn[24];
    if (head < 3) {
#pragma unroll
      for (int kk = 0; kk < 8; ++kk)
#pragma unroll
        for (int nt = 0; nt < 3; ++nt)
          Wn[kk * 3 + nt] = wfr[(((head + 1) * 12 + wave * 3 + nt) * 8 + kk) * 64 + lane];
    }

    // ---- C->LDS: D[n][xrow]: lane has 4 consecutive n-cols of row xrow
#pragma unroll
    for (int nt = 0; nt < 3; ++nt) {
      int nq = wave * 48 + nt * 16 + quad * 4;    // n base, 0..188
      int sel = nq >> 6, d0 = nq & 63;
      const float* bp = (sel == 0) ? bq : ((sel == 1) ? bk : bv);
      float4 bias = *(const float4*)(bp + head * 64 + d0);
#pragma unroll
      for (int mt = 0; mt < 5; ++mt) {
        int xr = mt * 16 + ln;
        uint2 p;
        p.x = cvt_pk_bf16(acc[mt][nt][0] + bias.x, acc[mt][nt][1] + bias.y);
        p.y = cvt_pk_bf16(acc[mt][nt][2] + bias.z, acc[mt][nt][3] + bias.w);
        *(uint2*)(&qkv[xr * 200 + nq]) = p;
      }
    }
    __syncthreads();

    // ---- attention S via MFMA: S[m,l] = mfma(K, Q), 2 tiles of 2 samples
    f32x4 s0 = {0.f, 0.f, 0.f, 0.f}, s1 = {0.f, 0.f, 0.f, 0.f};
    {
      const char* qb = (const char*)qkv;
#pragma unroll
      for (int kk = 0; kk < 2; ++kk) {
        bfrag qf0 = *(const bfrag*)(qb + bQ0 + kk * 64);          // Q cols 0..63
        bfrag kf0 = *(const bfrag*)(qb + bQ0 + 128 + kk * 64);    // K cols 64..127
        bfrag qf1 = *(const bfrag*)(qb + bQ1 + kk * 64);
        bfrag kf1 = *(const bfrag*)(qb + bQ1 + 128 + kk * 64);
        s0 = __builtin_amdgcn_mfma_f32_16x16x32_bf16(kf0, qf0, s0, 0, 0, 0);
        s1 = __builtin_amdgcn_mfma_f32_16x16x32_bf16(kf1, qf1, s1, 0, 0, 0);
      }
    }

    // ---- softmax over m (cross-quad) + w_m = 0.2*sum_l alpha (l-group)
    auto attn_tile = [&](const f32x4 sS, const int t) {
      float t0 = sS[0] * 0.0625f, t1 = sS[1] * 0.0625f;
      float t2 = sS[2] * 0.0625f, t3 = sS[3] * 0.0625f;
      float pm = lo ? fmaxf(fmaxf(t0, t1), fmaxf(t2, t3)) : (hi ? t0 : -1e30f);
      pm = fmaxf(pm, __shfl_xor(pm, 16));
      pm = fmaxf(pm, __shfl_xor(pm, 32));
      float e0 = __expf(t0 - pm), e1 = __expf(t1 - pm);
      float e2 = __expf(t2 - pm), e3 = __expf(t3 - pm);
      float ps = lo ? (e0 + e1 + e2 + e3) : (hi ? e0 : 0.f);
      ps += __shfl_xor(ps, 16);
      ps += __shfl_xor(ps, 32);
      float inv = 0.2f * __builtin_amdgcn_rcpf(ps);   // fold the 1/5 here
      float c0 = ((lo || hi) && lv) ? e0 * inv : 0.f;
      float c1 = (lo && lv) ? e1 * inv : 0.f;
      float c2 = (lo && lv) ? e2 * inv : 0.f;
      float c3 = (lo && lv) ? e3 * inv : 0.f;
      c0 = dppadd<0xB1>(c0); c0 = dppadd<0x4E>(c0); c0 += __shfl_xor(c0, 4);
      c1 = dppadd<0xB1>(c1); c1 = dppadd<0x4E>(c1); c1 += __shfl_xor(c1, 4);
      c2 = dppadd<0xB1>(c2); c2 = dppadd<0x4E>(c2); c2 += __shfl_xor(c2, 4);
      c3 = dppadd<0xB1>(c3); c3 = dppadd<0x4E>(c3); c3 += __shfl_xor(c3, 4);
      int smp = wave * 4 + t * 2 + sl;
      if (mm == 0) {
        if (qsel == 0) {
          *(float4*)(wgt + smp * 8) = make_float4(c0, c1, c2, c3);  // w[0..3]
        } else if (qsel == 1) {
          wgt[smp * 8 + 4] = c0;                                    // w[4]
        }
      }
    };
    attn_tile(s0, 0);
    attn_tile(s1, 1);
    __builtin_amdgcn_wave_barrier();   // wgt producer/consumer same wave

    // ---- phase D: s[head*64 + u*4 .. +3] = sum_m w[m] * V[m][.]
    {
      float4 w03 = *(const float4*)(wgt + sample * 8);
      float w4 = wgt[sample * 8 + 4];
      float a0 = 0.f, a1 = 0.f, a2 = 0.f, a3 = 0.f;
#pragma unroll
      for (int m = 0; m < 5; ++m) {
        float wv = (m == 0) ? w03.x : (m == 1) ? w03.y : (m == 2) ? w03.z
                 : (m == 3) ? w03.w : w4;
        uint2 v = *(const uint2*)(&qkv[(sample * 5 + m) * 200 + 128 + u * 4]);
        a0 += wv * bf2f((ushort)(v.x & 0xffff));
        a1 += wv * bf2f((ushort)(v.x >> 16));
        a2 += wv * bf2f((ushort)(v.y & 0xffff));
        a3 += wv * bf2f((ushort)(v.y >> 16));
      }
      uint2 p;
      p.x = cvt_pk_bf16(a0, a1);
      p.y = cvt_pk_bf16(a2, a3);
      *(uint2*)(&sbuf[sample * 256 + head * 64 + u * 4]) = p;
    }
    __syncthreads();   // protects qkv reuse (next head) / rbuf alias (SE)

    if (head < 3) {
#pragma unroll
      for (int i = 0; i < 24; ++i) Wc[i] = Wn[i];
    }
  }

  // ---- SE r-GEMM: rT[j][s] = relu(b1[j] + sum_c s[s][c]*W1[c][j]), hi/lo
  const bfrag* w1f = (const bfrag*)w1b;   // [2][8][64]
  f32x4 racc;
  {
    float4 b1v = *(const float4*)(b1 + quad * 4);
    racc[0] = b1v.x; racc[1] = b1v.y; racc[2] = b1v.z; racc[3] = b1v.w;
#pragma unroll
    for (int kk = 0; kk < 8; ++kk) {
      bfrag sB = *(const bfrag*)(&sbuf[ln * 256 + kk * 32 + quad * 8]);
      racc = __builtin_amdgcn_mfma_f32_16x16x32_bf16(w1f[kk * 64 + lane], sB, racc, 0, 0, 0);
      racc = __builtin_amdgcn_mfma_f32_16x16x32_bf16(w1f[512 + kk * 64 + lane], sB, racc, 0, 0, 0);
    }
#pragma unroll
    for (int r = 0; r < 4; ++r) racc[r] = fmaxf(racc[r], 0.f);
  }
  // r -> rbuf (ALIAS into dead qkv): [s][24] hi, +384 lo. All waves write
  // identical values (same A,B frags) -> benign race, no barrier needed.
  ushort* rb = qkv;
  {
    uint hx = cvt_pk_bf16(racc[0], racc[1]);
    uint hy = cvt_pk_bf16(racc[2], racc[3]);
    float l0 = racc[0] - __uint_as_float(hx << 16);
    float l1 = racc[1] - __uint_as_float(hx & 0xffff0000u);
    float l2 = racc[2] - __uint_as_float(hy << 16);
    float l3 = racc[3] - __uint_as_float(hy & 0xffff0000u);
    uint2 hp; hp.x = hx; hp.y = hy;
    uint2 lp; lp.x = cvt_pk_bf16(l0, l1); lp.y = cvt_pk_bf16(l2, l3);
    *(uint2*)(&rb[ln * 24 + quad * 4]) = hp;         // rT[j=quad*4+r][s=ln]
    *(uint2*)(&rb[384 + ln * 24 + quad * 4]) = lp;
  }

  // ---- SE g-GEMM: g[c][s] = sigmoid(b2[c] + sum_j r[s][j]*W2[j][c])
  //      wave w covers cols nt = w*4..w*4+3; direct packed float4 stores.
  const bfrag* w2f = (const bfrag*)w2b;   // [2][16][64]
  bfrag rH = {0, 0, 0, 0, 0, 0, 0, 0}, rL = {0, 0, 0, 0, 0, 0, 0, 0};
  if (quad < 2) {
    rH = *(const bfrag*)(&rb[ln * 24 + quad * 8]);
    rL = *(const bfrag*)(&rb[384 + ln * 24 + quad * 8]);
  }
  float* ob = out + ((size_t)blk * 16 + ln) * 256;
#pragma unroll
  for (int t = 0; t < 4; ++t) {
    int nt = wave * 4 + t;
    float4 b2v = *(const float4*)(b2 + nt * 16 + quad * 4);
    f32x4 g;
    g[0] = b2v.x; g[1] = b2v.y; g[2] = b2v.z; g[3] = b2v.w;
    bfrag wh = w2f[nt * 64 + lane];
    bfrag wl = w2f[1024 + nt * 64 + lane];
    g = __builtin_amdgcn_mfma_f32_16x16x32_bf16(wh, rH, g, 0, 0, 0);
    g = __builtin_amdgcn_mfma_f32_16x16x32_bf16(wh, rL, g, 0, 0, 0);
    g = __builtin_amdgcn_mfma_f32_16x16x32_bf16(wl, rH, g, 0, 0, 0);
    int c = nt * 16 + quad * 4;
    uint2 sv = *(const uint2*)(&sbuf[ln * 256 + c]);
    float4 ov;
    ov.x = sigmoidf(g[0]) * bf2f((ushort)(sv.x & 0xffff));
    ov.y = sigmoidf(g[1]) * bf2f((ushort)(sv.x >> 16));
    ov.z = sigmoidf(g[2]) * bf2f((ushort)(sv.y & 0xffff));
    ov.w = sigmoidf(g[3]) * bf2f((ushort)(sv.y >> 16));
    *(float4*)(ob + c) = ov;
  }
}

extern "C" void kernel_launch(void* const* d_in, const int* in_sizes, int n_in,
                              void* d_out, int out_size, void* d_ws, size_t ws_size,
                              hipStream_t stream) {
  const float* x  = (const float*)d_in[0];
  const float* Wq = (const float*)d_in[1];
  const float* bq = (const float*)d_in[2];
  const float* Wk = (const float*)d_in[3];
  const float* bk = (const float*)d_in[4];
  const float* Wv = (const float*)d_in[5];
  const float* bv = (const float*)d_in[6];
  const float* W1 = (const float*)d_in[7];
  const float* b1 = (const float*)d_in[8];
  const float* W2 = (const float*)d_in[9];
  const float* b2 = (const float*)d_in[10];

  ushort* wb  = (ushort*)d_ws;                          // 393216 B
  ushort* w1b = (ushort*)((char*)d_ws + 393216);        // 16384 B
  ushort* w2b = (ushort*)((char*)d_ws + 409600);        // 32768 B

  prep_kernel<<<768, 256, 0, stream>>>(Wq, Wk, Wv, W1, W2, wb, w1b, w2b);
  fused_kernel<<<6250, 256, 0, stream>>>(x, bq, bk, bv, wb, w1b, w2b, b1, b2,
                                         (float*)d_out);
}